// Round 1
// baseline (1269.140 us; speedup 1.0000x reference)
//
#include <hip/hip_runtime.h>

#if __has_builtin(__builtin_amdgcn_exp2f)
#define EXP2F(x) __builtin_amdgcn_exp2f(x)
#else
#define EXP2F(x) exp2f(x)
#endif
#if __has_builtin(__builtin_amdgcn_rcpf)
#define RCPF(x) __builtin_amdgcn_rcpf(x)
#else
#define RCPF(x) (1.0f / (x))
#endif

namespace {

constexpr int B_ = 2048, T_ = 512, D_ = 8, H_ = 20, L_ = 10;
constexpr int NB   = 3;        // batches per block (3*20 = 60 of 64 lanes)
constexpr int NW   = 5;        // waves per block; wave w owns layers 2w, 2w+1
constexpr int PAD  = 24;       // padded h row (floats): 96B, 16B-aligned
constexpr int NTHR = NW * 64;  // 320

__device__ __forceinline__ float tanh_fast(float x) {
    // tanh(x) = 1 - 2/(1 + e^{2x});  e^{2x} = 2^{x * 2*log2(e)}
    // x->+inf: exp2->inf, rcp->0 -> 1.  x->-inf: exp2->0 -> -1.  No NaN.
    float e = EXP2F(x * 2.8853900817779268f);
    return fmaf(-2.0f, RCPF(1.0f + e), 1.0f);
}

__device__ __forceinline__ void load20(const float* __restrict__ p, float* v) {
    float4 a = reinterpret_cast<const float4*>(p)[0];
    float4 b = reinterpret_cast<const float4*>(p)[1];
    float4 c = reinterpret_cast<const float4*>(p)[2];
    float4 d = reinterpret_cast<const float4*>(p)[3];
    float4 e = reinterpret_cast<const float4*>(p)[4];
    v[0]=a.x;  v[1]=a.y;  v[2]=a.z;  v[3]=a.w;
    v[4]=b.x;  v[5]=b.y;  v[6]=b.z;  v[7]=b.w;
    v[8]=c.x;  v[9]=c.y;  v[10]=c.z; v[11]=c.w;
    v[12]=d.x; v[13]=d.y; v[14]=d.z; v[15]=d.w;
    v[16]=e.x; v[17]=e.y; v[18]=e.z; v[19]=e.w;
}

__device__ __forceinline__ float dot20(const float* w, const float* v) {
    float s0 = 0.f, s1 = 0.f;   // two chains for FMA-latency hiding
    #pragma unroll
    for (int k = 0; k < 20; k += 2) {
        s0 = fmaf(w[k],     v[k],     s0);
        s1 = fmaf(w[k + 1], v[k + 1], s1);
    }
    return s0 + s1;
}

// Wavefront schedule over the (t, layer) grid: diagonal c processes cell
// (t = c - w, layers 2w & 2w+1) on wave w. h state double-buffered in LDS.
// MLP head for time th runs at diagonal th+NW (stage1: fc+relu+scale) and
// th+NW+1 (stage2: 20-lane sum + store), round-robined on wave th%NW.
__global__ __launch_bounds__(NTHR) void rnn_wavefront(
    const float* __restrict__ x,      // [B,T,8]
    const float* __restrict__ w_ih0,  // [20,8]
    const float* __restrict__ w_ih,   // [9,20,20]
    const float* __restrict__ w_hh,   // [10,20,20]
    const float* __restrict__ b_ih,   // [10,20]
    const float* __restrict__ b_hh,   // [10,20]
    const float* __restrict__ fc_w,   // [20,20]
    const float* __restrict__ fc_b,   // [20]
    const float* __restrict__ l2_w,   // [1,20]
    const float* __restrict__ l2_b,   // [1]
    float* __restrict__ out)          // [B,T,1] flat
{
    __shared__ __align__(16) float h_buf[2][L_][NB][PAD];
    __shared__ float p_buf[2][NB][H_];
    __shared__ float fcw_s[H_][H_ + 1];

    const int tid  = threadIdx.x;
    const int w    = tid >> 6;          // wave 0..4
    const int lane = tid & 63;
    const int bs   = lane / H_;         // 0..2 (3 = idle lanes 60..63)
    const int j    = lane % H_;
    const bool lane_ok = lane < NB * H_;
    const int bg   = blockIdx.x * NB + bs;
    const bool b_ok = lane_ok && (bg < B_);

    // zero h history (h0 = 0 for both parities) + stage fc_w
    for (int i = tid; i < 2 * L_ * NB * PAD; i += NTHR)
        (&h_buf[0][0][0][0])[i] = 0.f;
    for (int i = tid; i < H_ * H_; i += NTHR)
        fcw_s[i / H_][i % H_] = fc_w[i];

    // per-lane weight rows (VGPR-resident for the whole kernel)
    const int la = 2 * w, lb = 2 * w + 1;
    float wa[H_], wb[H_], wc[H_], wd[H_];
    #pragma unroll
    for (int k = 0; k < H_; ++k) {
        wa[k] = (la == 0) ? ((k < D_) ? w_ih0[j * D_ + k] : 0.f)
                          : w_ih[((la - 1) * H_ + j) * H_ + k];
        wb[k] = w_hh[(la * H_ + j) * H_ + k];
        wc[k] = w_ih[(la * H_ + j) * H_ + k];   // layer lb input wts = w_ih[lb-1]
        wd[k] = w_hh[(lb * H_ + j) * H_ + k];
    }
    const float bia  = b_ih[la * H_ + j] + b_hh[la * H_ + j];
    const float bib  = b_ih[lb * H_ + j] + b_hh[lb * H_ + j];
    const float fcbj = fc_b[j];
    const float l2wj = l2_w[j];
    const float l2bv = l2_b[0];

    __syncthreads();

    const int NDIAG = T_ + NW + 2;  // RNN tail ends c=515; head tail c=517
    for (int c = 0; c < NDIAG; ++c) {
        const int cur = c & 1, prv = cur ^ 1;
        const int t = c - w;
        const bool act = b_ok && ((unsigned)t < (unsigned)T_);

        // ---- cell A: layer la at time t ----
        if (act) {
            float hv[H_];
            load20(&h_buf[prv][la][bs][0], hv);
            float accA;
            if (w == 0) {
                const float* xp = x + ((size_t)bg * T_ + t) * D_;
                float4 xa = reinterpret_cast<const float4*>(xp)[0];
                float4 xb = reinterpret_cast<const float4*>(xp)[1];
                float s0 = fmaf(wa[0], xa.x, fmaf(wa[2], xa.z,
                           fmaf(wa[4], xb.x, fmaf(wa[6], xb.z, 0.f))));
                float s1 = fmaf(wa[1], xa.y, fmaf(wa[3], xa.w,
                           fmaf(wa[5], xb.y, fmaf(wa[7], xb.w, 0.f))));
                accA = s0 + s1;
            } else {
                float iv[H_];
                load20(&h_buf[prv][la - 1][bs][0], iv);
                accA = dot20(wa, iv);
            }
            accA += dot20(wb, hv) + bia;
            h_buf[cur][la][bs][j] = tanh_fast(accA);
        }
        __syncthreads();  // even-layer h visible (conservative; wave-local would do)

        // ---- cell B: layer lb at time t ----
        if (act) {
            float iv[H_], hv[H_];
            load20(&h_buf[cur][la][bs][0], iv);
            load20(&h_buf[prv][lb][bs][0], hv);
            float accB = dot20(wc, iv) + dot20(wd, hv) + bib;
            h_buf[cur][lb][bs][j] = tanh_fast(accB);
        }

        // ---- head stage 2: y for th2 = c-NW-1 (sum 20 partials, store) ----
        const int th2 = c - NW - 1;
        if ((unsigned)th2 < (unsigned)T_ && w == (th2 % NW) && lane < NB) {
            const int bo = blockIdx.x * NB + lane;
            if (bo < B_) {
                float s = l2bv;
                #pragma unroll
                for (int k = 0; k < H_; ++k) s += p_buf[prv][lane][k];
                out[(size_t)bo * T_ + th2] = s;
            }
        }

        // ---- head stage 1: th = c-NW (fc row j, relu, scale by l2_w[j]) ----
        const int th = c - NW;
        if ((unsigned)th < (unsigned)T_ && w == (th % NW) && b_ok) {
            float hv[H_];
            load20(&h_buf[prv][L_ - 1][bs][0], hv);
            float r = fcbj;
            #pragma unroll
            for (int k = 0; k < H_; ++k) r = fmaf(fcw_s[j][k], hv[k], r);
            r = fmaxf(r, 0.f);
            p_buf[cur][bs][j] = l2wj * r;
        }

        __syncthreads();  // publish cur-buffer writes; protect prv from next diag
    }
}

}  // namespace

extern "C" void kernel_launch(void* const* d_in, const int* in_sizes, int n_in,
                              void* d_out, int out_size, void* d_ws, size_t ws_size,
                              hipStream_t stream) {
    const float* x     = (const float*)d_in[0];
    const float* w_ih0 = (const float*)d_in[1];
    const float* w_ih  = (const float*)d_in[2];
    const float* w_hh  = (const float*)d_in[3];
    const float* b_ih  = (const float*)d_in[4];
    const float* b_hh  = (const float*)d_in[5];
    const float* fc_w  = (const float*)d_in[6];
    const float* fc_b  = (const float*)d_in[7];
    const float* l2_w  = (const float*)d_in[8];
    const float* l2_b  = (const float*)d_in[9];
    float* out = (float*)d_out;

    const int grid = (B_ + NB - 1) / NB;  // 683
    hipLaunchKernelGGL(rnn_wavefront, dim3(grid), dim3(NTHR), 0, stream,
                       x, w_ih0, w_ih, w_hh, b_ih, b_hh, fc_w, fc_b,
                       l2_w, l2_b, out);
}

// Round 2
// 967.434 us; speedup vs baseline: 1.3119x; 1.3119x over previous
//
#include <hip/hip_runtime.h>

#if __has_builtin(__builtin_amdgcn_exp2f)
#define EXP2F(x) __builtin_amdgcn_exp2f(x)
#else
#define EXP2F(x) exp2f(x)
#endif
#if __has_builtin(__builtin_amdgcn_rcpf)
#define RCPF(x) __builtin_amdgcn_rcpf(x)
#else
#define RCPF(x) (1.0f / (x))
#endif

namespace {

constexpr int B_ = 2048, T_ = 512, D_ = 8, H_ = 20, L_ = 10;
constexpr int NB   = 3;        // batches per block (3*20 = 60 of 64 lanes)
constexpr int NW   = 5;        // waves per block; wave w owns layers 2w, 2w+1
constexpr int PAD  = 24;       // padded h row (floats): 96B, 16B-aligned
constexpr int NTHR = NW * 64;  // 320

__device__ __forceinline__ float tanh_fast(float x) {
    // tanh(x) = 1 - 2/(1 + e^{2x});  e^{2x} = 2^{x * 2*log2(e)}
    // x->+inf: exp2->inf, rcp->0 -> 1.  x->-inf: exp2->0 -> -1.  No NaN.
    float e = EXP2F(x * 2.8853900817779268f);
    return fmaf(-2.0f, RCPF(1.0f + e), 1.0f);
}

// 20-elem dot: LDS row (float4-chunked) * VGPR weight row.
// 4 accumulator chains -> dep chain ~5 FMAs.
__device__ __forceinline__ float dot20_lds(const float* __restrict__ p,
                                           const float* w) {
    float s0 = 0.f, s1 = 0.f, s2 = 0.f, s3 = 0.f;
    #pragma unroll
    for (int c4 = 0; c4 < 5; ++c4) {
        float4 v = reinterpret_cast<const float4*>(p)[c4];
        s0 = fmaf(w[4 * c4 + 0], v.x, s0);
        s1 = fmaf(w[4 * c4 + 1], v.y, s1);
        s2 = fmaf(w[4 * c4 + 2], v.z, s2);
        s3 = fmaf(w[4 * c4 + 3], v.w, s3);
    }
    return (s0 + s1) + (s2 + s3);
}

// Wavefront schedule over the (t, layer) grid: diagonal c processes cell
// (t = c - w, layers 2w & 2w+1) on wave w. h state double-buffered in LDS.
// Single barrier per diagonal: cell B reads only its own wave's cell-A
// write; all cross-wave handoffs go through the prv-parity buffer.
// MLP head for time th runs at diagonal th+NW (stage1) and th+NW+1
// (stage2), both on wave th%NW.
__global__ __launch_bounds__(NTHR, 2) void rnn_wavefront(
    const float* __restrict__ x,      // [B,T,8]
    const float* __restrict__ w_ih0,  // [20,8]
    const float* __restrict__ w_ih,   // [9,20,20]
    const float* __restrict__ w_hh,   // [10,20,20]
    const float* __restrict__ b_ih,   // [10,20]
    const float* __restrict__ b_hh,   // [10,20]
    const float* __restrict__ fc_w,   // [20,20]
    const float* __restrict__ fc_b,   // [20]
    const float* __restrict__ l2_w,   // [1,20]
    const float* __restrict__ l2_b,   // [1]
    float* __restrict__ out)          // [B,T,1] flat
{
    __shared__ __align__(16) float h_buf[2][L_][NB][PAD];
    __shared__ float p_buf[2][NB][H_];
    __shared__ float fcw_s[H_][H_ + 1];

    const int tid  = threadIdx.x;
    const int w    = tid >> 6;          // wave 0..4
    const int lane = tid & 63;
    const int bs   = lane / H_;         // 0..2 (3 = idle lanes 60..63)
    const int j    = lane % H_;
    const bool lane_ok = lane < NB * H_;
    const int bg   = blockIdx.x * NB + bs;
    const bool b_ok = lane_ok && (bg < B_);

    // zero h history (h0 = 0 for both parities) + stage fc_w
    for (int i = tid; i < 2 * L_ * NB * PAD; i += NTHR)
        (&h_buf[0][0][0][0])[i] = 0.f;
    for (int i = tid; i < H_ * H_; i += NTHR)
        fcw_s[i / H_][i % H_] = fc_w[i];

    // per-lane weight rows (VGPR-resident for the whole kernel;
    // launch_bounds(...,2) caps VGPRs at 256 so these must NOT spill)
    const int la = 2 * w, lb = 2 * w + 1;
    float wa[H_], wb[H_], wc[H_], wd[H_];
    #pragma unroll
    for (int k = 0; k < H_; ++k) {
        wa[k] = (la == 0) ? ((k < D_) ? w_ih0[j * D_ + k] : 0.f)
                          : w_ih[((la - 1) * H_ + j) * H_ + k];
        wb[k] = w_hh[(la * H_ + j) * H_ + k];
        wc[k] = w_ih[(la * H_ + j) * H_ + k];   // layer lb input wts = w_ih[lb-1]
        wd[k] = w_hh[(lb * H_ + j) * H_ + k];
    }
    const float bia  = b_ih[la * H_ + j] + b_hh[la * H_ + j];
    const float bib  = b_ih[lb * H_ + j] + b_hh[lb * H_ + j];
    const float fcbj = fc_b[j];
    const float l2wj = l2_w[j];
    const float l2bv = l2_b[0];

    __syncthreads();

    const int NDIAG = T_ + NW + 1;  // RNN tail c=515; head stage2 tail c=517
    for (int c = 0; c < NDIAG; ++c) {
        const int cur = c & 1, prv = cur ^ 1;
        const int t = c - w;
        const bool act = b_ok && ((unsigned)t < (unsigned)T_);

        // ---- cell A: layer la at time t ----
        if (act) {
            float accA;
            if (w == 0) {
                const float* xp = x + ((size_t)bg * T_ + t) * D_;
                float4 xa = reinterpret_cast<const float4*>(xp)[0];
                float4 xb = reinterpret_cast<const float4*>(xp)[1];
                float s0 = fmaf(wa[0], xa.x, fmaf(wa[2], xa.z,
                           fmaf(wa[4], xb.x, fmaf(wa[6], xb.z, 0.f))));
                float s1 = fmaf(wa[1], xa.y, fmaf(wa[3], xa.w,
                           fmaf(wa[5], xb.y, fmaf(wa[7], xb.w, 0.f))));
                accA = s0 + s1;
            } else {
                accA = dot20_lds(&h_buf[prv][la - 1][bs][0], wa);
            }
            accA += dot20_lds(&h_buf[prv][la][bs][0], wb) + bia;
            h_buf[cur][la][bs][j] = tanh_fast(accA);
        }
        // (no barrier: cell B consumes only this wave's own write; the
        //  compiler orders same-wave LDS via lgkmcnt)

        // ---- cell B: layer lb at time t ----
        if (act) {
            float accB = dot20_lds(&h_buf[cur][la][bs][0], wc)
                       + dot20_lds(&h_buf[prv][lb][bs][0], wd) + bib;
            h_buf[cur][lb][bs][j] = tanh_fast(accB);
        }

        // ---- head stage 2: y for th2 = c-NW-1 (sum 20 partials, store) ----
        const int th2 = c - NW - 1;
        if ((unsigned)th2 < (unsigned)T_ && w == (th2 % NW) && lane < NB) {
            const int bo = blockIdx.x * NB + lane;
            if (bo < B_) {
                float s = l2bv;
                #pragma unroll
                for (int k = 0; k < H_; ++k) s += p_buf[prv][lane][k];
                out[(size_t)bo * T_ + th2] = s;
            }
        }

        // ---- head stage 1: th = c-NW (fc row j, relu, scale by l2_w[j]) ----
        const int th = c - NW;
        if ((unsigned)th < (unsigned)T_ && w == (th % NW) && b_ok) {
            float r = fcbj;
            const float* hv = &h_buf[prv][L_ - 1][bs][0];
            #pragma unroll
            for (int k = 0; k < H_; ++k) r = fmaf(fcw_s[j][k], hv[k], r);
            r = fmaxf(r, 0.f);
            p_buf[cur][bs][j] = l2wj * r;
        }

        __syncthreads();  // publish cur writes; protect next diagonal's WAR
    }
}

}  // namespace

extern "C" void kernel_launch(void* const* d_in, const int* in_sizes, int n_in,
                              void* d_out, int out_size, void* d_ws, size_t ws_size,
                              hipStream_t stream) {
    const float* x     = (const float*)d_in[0];
    const float* w_ih0 = (const float*)d_in[1];
    const float* w_ih  = (const float*)d_in[2];
    const float* w_hh  = (const float*)d_in[3];
    const float* b_ih  = (const float*)d_in[4];
    const float* b_hh  = (const float*)d_in[5];
    const float* fc_w  = (const float*)d_in[6];
    const float* fc_b  = (const float*)d_in[7];
    const float* l2_w  = (const float*)d_in[8];
    const float* l2_b  = (const float*)d_in[9];
    float* out = (float*)d_out;

    const int grid = (B_ + NB - 1) / NB;  // 683
    hipLaunchKernelGGL(rnn_wavefront, dim3(grid), dim3(NTHR), 0, stream,
                       x, w_ih0, w_ih, w_hh, b_ih, b_hh, fc_w, fc_b,
                       l2_w, l2_b, out);
}

// Round 3
// 720.105 us; speedup vs baseline: 1.7624x; 1.3435x over previous
//
#include <hip/hip_runtime.h>

#if __has_builtin(__builtin_amdgcn_exp2f)
#define EXP2F(x) __builtin_amdgcn_exp2f(x)
#else
#define EXP2F(x) exp2f(x)
#endif
#if __has_builtin(__builtin_amdgcn_rcpf)
#define RCPF(x) __builtin_amdgcn_rcpf(x)
#else
#define RCPF(x) (1.0f / (x))
#endif

namespace {

constexpr int B_ = 2048, T_ = 512, D_ = 8, H_ = 20, L_ = 10;
constexpr int NB   = 6;         // batches per block (lane = bs*10 + jp)
constexpr int JP   = 10;        // j-pairs per batch; lane computes rows 2jp,2jp+1
constexpr int NW   = L_;        // 10 waves; wave w owns layer w
constexpr int PAD  = 24;        // padded h row (floats): 96B, 16B-aligned
constexpr int NTHR = NW * 64;   // 640

__device__ __forceinline__ float tanh_fast(float x) {
    // tanh(x) = 1 - 2/(1 + e^{2x}); e^{2x} = 2^(x*2*log2 e). Saturates w/o NaN.
    float e = EXP2F(x * 2.8853900817779268f);
    return fmaf(-2.0f, RCPF(1.0f + e), 1.0f);
}

// Wavefront over the (t, layer) grid: diagonal c -> wave w computes layer w
// at t = c - w for 6 batches (lanes: bs 0..5 x jp 0..9, 2 hidden rows each).
// h double-buffered in LDS by diagonal parity; ONE barrier per diagonal.
// Weights (2 w_ih rows + 2 w_hh rows = 80 floats) live in VGPRs; the
// amdgpu_waves_per_eu(2,2) attr stops the allocator from spilling them to
// chase occupancy (R2 failure: VGPR=64 with 80 live floats).
// MLP head runs on wave 0 (its cell dot is only 8 wide): stage1 at lag 10,
// stage2 (sum over jp + store) at lag 11, fc weights in wave-0 registers.
__global__ __launch_bounds__(NTHR)
__attribute__((amdgpu_waves_per_eu(2, 2)))
void rnn_wavefront(
    const float* __restrict__ x,      // [B,T,8]
    const float* __restrict__ w_ih0,  // [20,8]
    const float* __restrict__ w_ih,   // [9,20,20]
    const float* __restrict__ w_hh,   // [10,20,20]
    const float* __restrict__ b_ih,   // [10,20]
    const float* __restrict__ b_hh,   // [10,20]
    const float* __restrict__ fc_w,   // [20,20]
    const float* __restrict__ fc_b,   // [20]
    const float* __restrict__ l2_w,   // [1,20]
    const float* __restrict__ l2_b,   // [1]
    float* __restrict__ out)          // [B,T,1] flat
{
    __shared__ __align__(16) float h_buf[2][L_][NB][PAD];
    __shared__ __align__(16) float p_buf[2][NB][12];

    const int tid  = threadIdx.x;
    const int w    = tid >> 6;            // wave = layer 0..9
    const int lane = tid & 63;
    const int bs   = lane / JP;           // 0..5 (6 = idle lanes 60..63)
    const int jp   = lane % JP;           // j-pair 0..9
    const bool lane_ok = lane < NB * JP;
    const int bg   = blockIdx.x * NB + bs;
    const bool b_ok = lane_ok && (bg < B_);
    const int j0 = 2 * jp, j1 = 2 * jp + 1;

    // zero h history (h0 = 0, both parities)
    for (int i = tid; i < 2 * L_ * NB * PAD; i += NTHR)
        (&h_buf[0][0][0][0])[i] = 0.f;

    // ---- per-lane weight rows (VGPR-resident all kernel) ----
    float wi0[H_], wi1[H_], wh0[H_], wh1[H_];
    #pragma unroll
    for (int k = 0; k < H_; ++k) {
        if (w == 0) {
            wi0[k] = (k < D_) ? w_ih0[j0 * D_ + k] : 0.f;
            wi1[k] = (k < D_) ? w_ih0[j1 * D_ + k] : 0.f;
        } else {
            wi0[k] = w_ih[((w - 1) * H_ + j0) * H_ + k];
            wi1[k] = w_ih[((w - 1) * H_ + j1) * H_ + k];
        }
        wh0[k] = w_hh[(w * H_ + j0) * H_ + k];
        wh1[k] = w_hh[(w * H_ + j1) * H_ + k];
    }
    const float bia0 = b_ih[w * H_ + j0] + b_hh[w * H_ + j0];
    const float bia1 = b_ih[w * H_ + j1] + b_hh[w * H_ + j1];

    // ---- head weights, wave 0 only (regs live only on w==0 path) ----
    float fw0[H_], fw1[H_];
    float fb0 = 0.f, fb1 = 0.f, lw0 = 0.f, lw1 = 0.f, lbv = 0.f;
    if (w == 0) {
        #pragma unroll
        for (int k = 0; k < H_; ++k) {
            fw0[k] = fc_w[j0 * H_ + k];
            fw1[k] = fc_w[j1 * H_ + k];
        }
        fb0 = fc_b[j0]; fb1 = fc_b[j1];
        lw0 = l2_w[j0]; lw1 = l2_w[j1];
        lbv = l2_b[0];
    }

    __syncthreads();

    const int NDIAG = T_ + NW + 1;  // 523: RNN tail c=520, head tail c=522
    for (int c = 0; c < NDIAG; ++c) {
        const int cur = c & 1, prv = cur ^ 1;
        const int t = c - w;

        if (b_ok && (unsigned)t < (unsigned)T_) {
            float a0 = bia0, a1 = bia1;
            if (w == 0) {
                const float* xp = x + ((size_t)bg * T_ + t) * D_;
                float4 xa = reinterpret_cast<const float4*>(xp)[0];
                float4 xb = reinterpret_cast<const float4*>(xp)[1];
                a0 = fmaf(wi0[0], xa.x, a0); a1 = fmaf(wi1[0], xa.x, a1);
                a0 = fmaf(wi0[1], xa.y, a0); a1 = fmaf(wi1[1], xa.y, a1);
                a0 = fmaf(wi0[2], xa.z, a0); a1 = fmaf(wi1[2], xa.z, a1);
                a0 = fmaf(wi0[3], xa.w, a0); a1 = fmaf(wi1[3], xa.w, a1);
                a0 = fmaf(wi0[4], xb.x, a0); a1 = fmaf(wi1[4], xb.x, a1);
                a0 = fmaf(wi0[5], xb.y, a0); a1 = fmaf(wi1[5], xb.y, a1);
                a0 = fmaf(wi0[6], xb.z, a0); a1 = fmaf(wi1[6], xb.z, a1);
                a0 = fmaf(wi0[7], xb.w, a0); a1 = fmaf(wi1[7], xb.w, a1);
            } else {
                const float4* ip = reinterpret_cast<const float4*>(
                    &h_buf[prv][w - 1][bs][0]);
                #pragma unroll
                for (int q = 0; q < 5; ++q) {
                    float4 v = ip[q];
                    a0 = fmaf(wi0[4*q+0], v.x, a0); a1 = fmaf(wi1[4*q+0], v.x, a1);
                    a0 = fmaf(wi0[4*q+1], v.y, a0); a1 = fmaf(wi1[4*q+1], v.y, a1);
                    a0 = fmaf(wi0[4*q+2], v.z, a0); a1 = fmaf(wi1[4*q+2], v.z, a1);
                    a0 = fmaf(wi0[4*q+3], v.w, a0); a1 = fmaf(wi1[4*q+3], v.w, a1);
                }
            }
            const float4* hp = reinterpret_cast<const float4*>(
                &h_buf[prv][w][bs][0]);
            #pragma unroll
            for (int q = 0; q < 5; ++q) {
                float4 v = hp[q];
                a0 = fmaf(wh0[4*q+0], v.x, a0); a1 = fmaf(wh1[4*q+0], v.x, a1);
                a0 = fmaf(wh0[4*q+1], v.y, a0); a1 = fmaf(wh1[4*q+1], v.y, a1);
                a0 = fmaf(wh0[4*q+2], v.z, a0); a1 = fmaf(wh1[4*q+2], v.z, a1);
                a0 = fmaf(wh0[4*q+3], v.w, a0); a1 = fmaf(wh1[4*q+3], v.w, a1);
            }
            float2 hn = { tanh_fast(a0), tanh_fast(a1) };
            *reinterpret_cast<float2*>(&h_buf[cur][w][bs][2 * jp]) = hn;
        }

        if (w == 0) {
            // head stage 1: th1 = c-10 (fc rows j0,j1 + relu + l2 scale)
            const int th1 = c - NW;
            if ((unsigned)th1 < (unsigned)T_ && b_ok) {
                const float4* hv = reinterpret_cast<const float4*>(
                    &h_buf[prv][L_ - 1][bs][0]);
                float r0 = fb0, r1 = fb1;
                #pragma unroll
                for (int q = 0; q < 5; ++q) {
                    float4 v = hv[q];
                    r0 = fmaf(fw0[4*q+0], v.x, r0); r1 = fmaf(fw1[4*q+0], v.x, r1);
                    r0 = fmaf(fw0[4*q+1], v.y, r0); r1 = fmaf(fw1[4*q+1], v.y, r1);
                    r0 = fmaf(fw0[4*q+2], v.z, r0); r1 = fmaf(fw1[4*q+2], v.z, r1);
                    r0 = fmaf(fw0[4*q+3], v.w, r0); r1 = fmaf(fw1[4*q+3], v.w, r1);
                }
                p_buf[cur][bs][jp] = fmaf(lw0, fmaxf(r0, 0.f),
                                          lw1 * fmaxf(r1, 0.f));
            }
            // head stage 2: th2 = c-11 (sum 10 partials per batch, store)
            const int th2 = c - NW - 1;
            if ((unsigned)th2 < (unsigned)T_ && lane < NB) {
                const int bo = blockIdx.x * NB + lane;
                if (bo < B_) {
                    const float2* pp = reinterpret_cast<const float2*>(
                        &p_buf[prv][lane][0]);
                    float s = lbv;
                    #pragma unroll
                    for (int q = 0; q < 5; ++q) {
                        float2 v = pp[q];
                        s += v.x + v.y;
                    }
                    out[(size_t)bo * T_ + th2] = s;
                }
            }
        }

        __syncthreads();  // publish cur writes; protect prv for next diagonal
    }
}

}  // namespace

extern "C" void kernel_launch(void* const* d_in, const int* in_sizes, int n_in,
                              void* d_out, int out_size, void* d_ws, size_t ws_size,
                              hipStream_t stream) {
    const float* x     = (const float*)d_in[0];
    const float* w_ih0 = (const float*)d_in[1];
    const float* w_ih  = (const float*)d_in[2];
    const float* w_hh  = (const float*)d_in[3];
    const float* b_ih  = (const float*)d_in[4];
    const float* b_hh  = (const float*)d_in[5];
    const float* fc_w  = (const float*)d_in[6];
    const float* fc_b  = (const float*)d_in[7];
    const float* l2_w  = (const float*)d_in[8];
    const float* l2_b  = (const float*)d_in[9];
    float* out = (float*)d_out;

    const int grid = (B_ + NB - 1) / NB;  // 342
    hipLaunchKernelGGL(rnn_wavefront, dim3(grid), dim3(NTHR), 0, stream,
                       x, w_ih0, w_ih, w_hh, b_ih, b_hh, fc_w, fc_b,
                       l2_w, l2_b, out);
}